// Round 8
// baseline (104.408 us; speedup 1.0000x reference)
//
#include <hip/hip_runtime.h>
#include <math.h>
#include <stdint.h>

// B,K,V,T,S,H = 128,10,50257,20,4,2048; t read from input.
#define NB 128
#define NK 10
#define NV 50257
#define NT 20
#define NS 4
#define NH 2048

#define TPW 384    // threads per topk block (6 waves): 5 blocks/CU = 30 waves, all resident
#define NWV 6
#define QCAP 576   // = QTRIG + 512 (max appends/iter/wave) + slack
#define QTRIG 48

// Monotone bijection float->u32 (no NaNs in data). key==0 unreachable.
__device__ __forceinline__ unsigned key_of(float f) {
    unsigned u = __float_as_uint(f);
    unsigned m = (unsigned)((int)u >> 31) | 0x80000000u;
    return u ^ m;
}
__device__ __forceinline__ float val_of(unsigned k) {
    unsigned m = (k & 0x80000000u) ? 0x80000000u : 0xFFFFFFFFu;
    return __uint_as_float(k ^ m);
}
__device__ __forceinline__ float rdlanef(float v, int l) {
    return __uint_as_float((unsigned)__builtin_amdgcn_readlane((int)__float_as_uint(v), l));
}

// ---------------------------------------------------------------------------
// Kernel 1: per-(b,k) row top-10. 6 waves/row. Safe-threshold filter +
// per-wave LDS candidate queue + lazy exact compaction. 2-deep load
// pipeline (4 dwordx4 in flight per lane).
// ---------------------------------------------------------------------------
__global__ __launch_bounds__(TPW, 8) void topk_rows(const float* __restrict__ lp,
                                                    float* __restrict__ ys,   // (B*K,10)
                                                    int*   __restrict__ ix) { // (B*K,10)
    const int row  = blockIdx.x;
    const int tid  = threadIdx.x;
    const int lane = tid & 63;
    const int wave = tid >> 6;                // 0..5
    const float* rowp = lp + (size_t)row * NV;

    __shared__ unsigned long long Q[NWV][QCAP];
    __shared__ int qcnt[NWV];

    if (lane == 0) qcnt[wave] = 0;
    __threadfence_block();

    float thr = -INFINITY;

    auto lane_append = [&](float v, int idx) {
        if (v >= thr) {
            int p = atomicAdd(&qcnt[wave], 1);
            Q[wave][p] = ((unsigned long long)key_of(v) << 32) | (unsigned)(~(unsigned)idx);
        }
    };

    // Wave-local exact top-10 via rank-count; leaves Q[0..9] sorted desc,
    // count=10, thr = 10th value.
    auto compact = [&]() {
        __threadfence_block();
        int cnt = qcnt[wave];
        if (cnt > 10) {
            if (cnt <= 64) {
                unsigned long long mine = (lane < cnt) ? Q[wave][lane] : 0ull;
                int rk = 0;
                for (int j = 0; j < cnt; ++j)
                    rk += (Q[wave][j] > mine) ? 1 : 0;   // u64s distinct
                __threadfence_block();
                if (lane < cnt && rk < 10) Q[wave][rk] = mine;
            } else {
                unsigned long long mine[9];
                int rk[9];
#pragma unroll
                for (int s = 0; s < 9; ++s) {
                    int e = lane + (s << 6);
                    mine[s] = (e < cnt) ? Q[wave][e] : 0ull;
                    rk[s] = 0;
                }
                for (int j = 0; j < cnt; ++j) {
                    unsigned long long qv = Q[wave][j];
#pragma unroll
                    for (int s = 0; s < 9; ++s) rk[s] += (qv > mine[s]) ? 1 : 0;
                }
                __threadfence_block();
#pragma unroll
                for (int s = 0; s < 9; ++s) {
                    int e = lane + (s << 6);
                    if (e < cnt && rk[s] < 10) Q[wave][rk[s]] = mine[s];
                }
            }
            if (lane == 0) qcnt[wave] = 10;
            __threadfence_block();
            thr = val_of((unsigned)(Q[wave][9] >> 32));
        }
    };

    // b's element offset from a's: 4*TPW = 1536.
    auto process8 = [&](float4 a, float4 b, int basea) {
        float m8 = fmaxf(fmaxf(fmaxf(a.x, a.y), fmaxf(a.z, a.w)),
                         fmaxf(fmaxf(b.x, b.y), fmaxf(b.z, b.w)));
        if (__ballot(m8 >= thr)) {            // rare after priming
            lane_append(a.x, basea + 0);
            lane_append(a.y, basea + 1);
            lane_append(a.z, basea + 2);
            lane_append(a.w, basea + 3);
            lane_append(b.x, basea + 1536);
            lane_append(b.y, basea + 1537);
            lane_append(b.z, basea + 1538);
            lane_append(b.w, basea + 1539);
            __threadfence_block();
            if (qcnt[wave] >= QTRIG) compact();
        }
    };

    const int head = (int)(((16u - (unsigned)((uintptr_t)rowp & 15u)) & 15u) >> 2);
    const int n4 = (NV - 1 - head) >> 2;      // float4s; last element in tail
    const int NFULL = n4 / (2 * TPW);         // full 768-f4 iterations (~16)
    const float4* rowp4 = (const float4*)(rowp + head);

    // ---- iteration 0 + threshold priming; 2-deep prefetch ----
    float4 a0  = rowp4[tid];
    float4 b0  = rowp4[tid + TPW];
    float4 p0a = rowp4[2 * TPW + tid];        // data for it=1
    float4 p0b = rowp4[3 * TPW + tid];
    float4 p1a = rowp4[4 * TPW + tid];        // data for it=2 (NFULL >= 3)
    float4 p1b = rowp4[5 * TPW + tid];

    float m8 = fmaxf(fmaxf(fmaxf(a0.x, a0.y), fmaxf(a0.z, a0.w)),
                     fmaxf(fmaxf(b0.x, b0.y), fmaxf(b0.z, b0.w)));
    int rank = 0;
    for (int j = 0; j < 64; ++j) {
        float o = rdlanef(m8, j);
        rank += ((o > m8) || (o == m8 && j < lane)) ? 1 : 0;
    }
    // thr = 10th-largest lane-max8 of this wave's iter-0 slice: >=10 of its
    // elements are >= thr -> wave-locally safe.
    {
        unsigned long long b9 = __ballot(rank == 9);
        int l9 = (int)__builtin_ctzll(b9);
        thr = rdlanef(m8, l9);
    }
    {
        int basea = head + 4 * tid;
        lane_append(a0.x, basea + 0);
        lane_append(a0.y, basea + 1);
        lane_append(a0.z, basea + 2);
        lane_append(a0.w, basea + 3);
        lane_append(b0.x, basea + 1536);
        lane_append(b0.y, basea + 1537);
        lane_append(b0.z, basea + 1538);
        lane_append(b0.w, basea + 1539);
        __threadfence_block();
        if (qcnt[wave] >= QTRIG) compact();
    }

    // ---- main loop: consume p0, shift p1->p0, prefetch it+2 ----
    for (int it = 1; it < NFULL; ++it) {
        float4 ca = p0a, cb = p0b;
        p0a = p1a; p0b = p1b;
        if (it + 2 < NFULL) {
            p1a = rowp4[(it + 2) * 2 * TPW + tid];
            p1b = rowp4[(it + 2) * 2 * TPW + TPW + tid];
        }
        process8(ca, cb, head + 4 * (it * 2 * TPW + tid));
    }
    // remainder float4s: [NFULL*768, n4)
    {
        int ja = NFULL * 2 * TPW + tid;
        int jb = ja + TPW;
        float4 a = (ja < n4) ? rowp4[ja]
                             : make_float4(-INFINITY, -INFINITY, -INFINITY, -INFINITY);
        float4 b = (jb < n4) ? rowp4[jb]
                             : make_float4(-INFINITY, -INFINITY, -INFINITY, -INFINITY);
        process8(a, b, head + 4 * ja);
    }
    // scalar head + tail (incl. penalized last element) on wave 0
    if (wave == 0) {
        if (lane < head) lane_append(rowp[lane], lane);
        int idx = head + 4 * n4 + lane;
        if (idx < NV) {
            float v = rowp[idx];
            if (idx == NV - 1) v -= 1000.0f;
            lane_append(v, idx);
        }
    }

    compact();
    __syncthreads();

    // merge 6 wave top-10s (60 distinct u64s) by rank-count
    if (tid < 60) {
        int w = tid / 10, r = tid - w * 10;
        unsigned long long my = Q[w][r];
        int rnk = 0;
#pragma unroll
        for (int w2 = 0; w2 < NWV; ++w2)
            for (int r2 = 0; r2 < 10; ++r2)
                rnk += (Q[w2][r2] > my) ? 1 : 0;
        if (rnk < 10) {
            ys[row * 10 + rnk] = val_of((unsigned)(my >> 32));
            ix[row * 10 + rnk] = (int)(~(unsigned)(my & 0xFFFFFFFFull));
        }
    }
}

// ---------------------------------------------------------------------------
// Kernel 2 (fused select + gather): one block per (b,s); each block computes
// the batch's selection once, then copies all 10 state rows (2-row unrolled
// -> 4 loads in flight; repeated q_sel rows hit L1). s==0 blocks also write
// seq / seq_lp / p.
// ---------------------------------------------------------------------------
__global__ __launch_bounds__(256) void select_gather(
    const float* __restrict__ lp_sum,   // (B,K)
    const float* __restrict__ seq_lp,   // (B,T,K)
    const int*   __restrict__ seq,      // (B,T,K) int32
    const int*   __restrict__ tptr,     // scalar t
    const float* __restrict__ ys,       // (B*K,10)
    const int*   __restrict__ ix,       // (B*K,10)
    const float* __restrict__ st,       // (B,S,K,H)
    float* __restrict__ out_seq,        // (B,T,K) as float
    float* __restrict__ out_seq_lp,     // (B,T,K)
    float* __restrict__ out_p,          // (B,K)
    float* __restrict__ out_st)         // (B,S,K,H)
{
    const int bs  = blockIdx.x;          // b*NS + s
    const int b   = bs / NS;
    const int s   = bs - b * NS;
    const int tid = threadIdx.x;

    __shared__ float sf[100];
    __shared__ int   so[10];
    __shared__ int   sq[10];
    __shared__ int   stok[10];
    __shared__ float sr[10];

    if (tid < 100) {
        int c = tid / 10, q = tid % 10;  // flat f = c*K + q
        sf[tid] = lp_sum[b * 10 + q] + ys[(b * 10 + q) * 10 + c];
    }
    __syncthreads();
    if (tid < 100) {
        float v = sf[tid];
        int rank = 0;
        for (int j = 0; j < 100; ++j) {
            float u = sf[j];
            rank += (u > v || (u == v && j < tid)) ? 1 : 0; // argsort-stable
        }
        if (rank < 10) so[rank] = tid;
    }
    __syncthreads();

    // --- gather 10 state rows, 2 rows per step (4 loads in flight) ---
    const float* src_base = st + (size_t)bs * NK * NH;
    float*       dst_base = out_st + (size_t)bs * NK * NH;
#pragma unroll
    for (int kk = 0; kk < 10; kk += 2) {
        const int q0 = so[kk] % 10;
        const int q1 = so[kk + 1] % 10;
        const float4* s0 = (const float4*)(src_base + (size_t)q0 * NH);
        const float4* s1 = (const float4*)(src_base + (size_t)q1 * NH);
        float4 x0 = s0[tid];
        float4 x1 = s0[tid + 256];
        float4 y0 = s1[tid];
        float4 y1 = s1[tid + 256];
        float4* d0 = (float4*)(dst_base + (size_t)kk * NH);
        float4* d1 = (float4*)(dst_base + (size_t)(kk + 1) * NH);
        d0[tid]       = x0;
        d0[tid + 256] = x1;
        d1[tid]       = y0;
        d1[tid + 256] = y1;
    }

    // --- one block per batch writes seq outputs (block-uniform branch) ---
    if (s == 0) {
        const int t = tptr[0];
        if (tid < 10) {
            int f = so[tid];
            int c = f / 10, qq = f % 10;
            sq[tid]   = qq;
            stok[tid] = ix[(b * 10 + qq) * 10 + c];
            sr[tid]   = ys[(b * 10 + qq) * 10 + c];
            out_p[b * 10 + tid] = sf[f];
        }
        __syncthreads();
        if (tid < NT * NK) {                 // 200 < 256: single pass
            int time = tid / 10, kk = tid % 10;
            int qs = sq[kk];
            int src_k = (time < t) ? qs : kk;
            int   sval = seq[(b * NT + time) * 10 + src_k];
            float lv = seq_lp[(b * NT + time) * 10 + src_k];
            if (time == t) { sval = stok[kk]; lv = sr[kk]; }
            out_seq[(b * NT + time) * 10 + kk]    = (float)sval; // exact <2^24
            out_seq_lp[(b * NT + time) * 10 + kk] = lv;
        }
    }
}

extern "C" void kernel_launch(void* const* d_in, const int* in_sizes, int n_in,
                              void* d_out, int out_size, void* d_ws, size_t ws_size,
                              hipStream_t stream) {
    const float* lp      = (const float*)d_in[0];  // (B,K,V)
    const float* lp_sum  = (const float*)d_in[1];  // (B,K)
    const float* seq_lp  = (const float*)d_in[2];  // (B,T,K)
    const float* st      = (const float*)d_in[3];  // (B,S,K,H)
    const int*   seq     = (const int*)d_in[4];    // (B,T,K)
    const int*   tptr    = (const int*)d_in[5];    // scalar t

    float* out        = (float*)d_out;
    float* out_seq    = out;                         // 25600
    float* out_seq_lp = out + NB * NT * NK;          // +25600
    float* out_p      = out + 2 * NB * NT * NK;      // +1280
    float* out_st     = out + 2 * NB * NT * NK + NB * NK;

    float* ws_ys   = (float*)d_ws;                   // 12800 floats
    int*   ws_ix   = (int*)((char*)d_ws + 51200);    // 12800 ints

    topk_rows<<<NB * NK, TPW, 0, stream>>>(lp, ws_ys, ws_ix);
    select_gather<<<NB * NS, 256, 0, stream>>>(
        lp_sum, seq_lp, seq, tptr, ws_ys, ws_ix, st,
        out_seq, out_seq_lp, out_p, out_st);
}

// Round 9
// 72.717 us; speedup vs baseline: 1.4358x; 1.4358x over previous
//
#include <hip/hip_runtime.h>
#include <math.h>
#include <stdint.h>

// B,K,V,T,S,H = 128,10,50257,20,4,2048; t read from input.
#define NB 128
#define NK 10
#define NV 50257
#define NT 20
#define NS 4
#define NH 2048

#define TPW 320    // 5 waves/row: 5 blocks/CU co-resident (25 waves), LDS 115KB/CU
#define NWV 5
#define QCAP 576   // = QTRIG + 512 (max appends/iter/wave) + slack
#define QTRIG 48

// Monotone bijection float->u32 (no NaNs in data). key==0 unreachable.
__device__ __forceinline__ unsigned key_of(float f) {
    unsigned u = __float_as_uint(f);
    unsigned m = (unsigned)((int)u >> 31) | 0x80000000u;
    return u ^ m;
}
__device__ __forceinline__ float val_of(unsigned k) {
    unsigned m = (k & 0x80000000u) ? 0x80000000u : 0xFFFFFFFFu;
    return __uint_as_float(k ^ m);
}
__device__ __forceinline__ float rdlanef(float v, int l) {
    return __uint_as_float((unsigned)__builtin_amdgcn_readlane((int)__float_as_uint(v), l));
}

// ---------------------------------------------------------------------------
// Kernel 1: per-(b,k) row top-10. 5 waves/row. Safe-threshold filter +
// per-wave LDS candidate queue + lazy exact compaction. 2-deep load
// pipeline (4 dwordx4 in flight per lane). No min-waves launch bound:
// let the allocator use what it needs (R7 lesson: a 64-VGPR cap spills).
// ---------------------------------------------------------------------------
__global__ __launch_bounds__(TPW) void topk_rows(const float* __restrict__ lp,
                                                 float* __restrict__ ys,   // (B*K,10)
                                                 int*   __restrict__ ix) { // (B*K,10)
    const int row  = blockIdx.x;
    const int tid  = threadIdx.x;
    const int lane = tid & 63;
    const int wave = tid >> 6;                // 0..4
    const float* rowp = lp + (size_t)row * NV;

    __shared__ unsigned long long Q[NWV][QCAP];
    __shared__ int qcnt[NWV];

    if (lane == 0) qcnt[wave] = 0;
    __threadfence_block();

    float thr = -INFINITY;

    auto lane_append = [&](float v, int idx) {
        if (v >= thr) {
            int p = atomicAdd(&qcnt[wave], 1);
            Q[wave][p] = ((unsigned long long)key_of(v) << 32) | (unsigned)(~(unsigned)idx);
        }
    };

    // Wave-local exact top-10 via rank-count; leaves Q[0..9] sorted desc,
    // count=10, thr = 10th value.
    auto compact = [&]() {
        __threadfence_block();
        int cnt = qcnt[wave];
        if (cnt > 10) {
            if (cnt <= 64) {
                unsigned long long mine = (lane < cnt) ? Q[wave][lane] : 0ull;
                int rk = 0;
                for (int j = 0; j < cnt; ++j)
                    rk += (Q[wave][j] > mine) ? 1 : 0;   // u64s distinct
                __threadfence_block();
                if (lane < cnt && rk < 10) Q[wave][rk] = mine;
            } else {
                unsigned long long mine[9];
                int rk[9];
#pragma unroll
                for (int s = 0; s < 9; ++s) {
                    int e = lane + (s << 6);
                    mine[s] = (e < cnt) ? Q[wave][e] : 0ull;
                    rk[s] = 0;
                }
                for (int j = 0; j < cnt; ++j) {
                    unsigned long long qv = Q[wave][j];
#pragma unroll
                    for (int s = 0; s < 9; ++s) rk[s] += (qv > mine[s]) ? 1 : 0;
                }
                __threadfence_block();
#pragma unroll
                for (int s = 0; s < 9; ++s) {
                    int e = lane + (s << 6);
                    if (e < cnt && rk[s] < 10) Q[wave][rk[s]] = mine[s];
                }
            }
            if (lane == 0) qcnt[wave] = 10;
            __threadfence_block();
            thr = val_of((unsigned)(Q[wave][9] >> 32));
        }
    };

    // b's element offset from a's: 4*TPW = 1280.
    auto process8 = [&](float4 a, float4 b, int basea) {
        float m8 = fmaxf(fmaxf(fmaxf(a.x, a.y), fmaxf(a.z, a.w)),
                         fmaxf(fmaxf(b.x, b.y), fmaxf(b.z, b.w)));
        if (__ballot(m8 >= thr)) {            // rare after priming
            lane_append(a.x, basea + 0);
            lane_append(a.y, basea + 1);
            lane_append(a.z, basea + 2);
            lane_append(a.w, basea + 3);
            lane_append(b.x, basea + 1280);
            lane_append(b.y, basea + 1281);
            lane_append(b.z, basea + 1282);
            lane_append(b.w, basea + 1283);
            __threadfence_block();
            if (qcnt[wave] >= QTRIG) compact();
        }
    };

    const int head = (int)(((16u - (unsigned)((uintptr_t)rowp & 15u)) & 15u) >> 2);
    const int n4 = (NV - 1 - head) >> 2;      // float4s; last element in tail
    const int NFULL = n4 / (2 * TPW);         // full 640-f4 iterations (19)
    const float4* rowp4 = (const float4*)(rowp + head);

    // ---- iteration 0 + threshold priming; 2-deep prefetch ----
    float4 a0  = rowp4[tid];
    float4 b0  = rowp4[tid + TPW];
    float4 p0a = rowp4[2 * TPW + tid];        // data for it=1
    float4 p0b = rowp4[3 * TPW + tid];
    float4 p1a = rowp4[4 * TPW + tid];        // data for it=2 (NFULL >= 3)
    float4 p1b = rowp4[5 * TPW + tid];

    float m8 = fmaxf(fmaxf(fmaxf(a0.x, a0.y), fmaxf(a0.z, a0.w)),
                     fmaxf(fmaxf(b0.x, b0.y), fmaxf(b0.z, b0.w)));
    int rank = 0;
    for (int j = 0; j < 64; ++j) {
        float o = rdlanef(m8, j);
        rank += ((o > m8) || (o == m8 && j < lane)) ? 1 : 0;
    }
    // thr = 10th-largest lane-max8 of this wave's iter-0 slice: >=10 of its
    // elements are >= thr -> wave-locally safe.
    {
        unsigned long long b9 = __ballot(rank == 9);
        int l9 = (int)__builtin_ctzll(b9);
        thr = rdlanef(m8, l9);
    }
    {
        int basea = head + 4 * tid;
        lane_append(a0.x, basea + 0);
        lane_append(a0.y, basea + 1);
        lane_append(a0.z, basea + 2);
        lane_append(a0.w, basea + 3);
        lane_append(b0.x, basea + 1280);
        lane_append(b0.y, basea + 1281);
        lane_append(b0.z, basea + 1282);
        lane_append(b0.w, basea + 1283);
        __threadfence_block();
        if (qcnt[wave] >= QTRIG) compact();
    }

    // ---- main loop: consume p0, shift p1->p0, prefetch it+2 ----
    for (int it = 1; it < NFULL; ++it) {
        float4 ca = p0a, cb = p0b;
        p0a = p1a; p0b = p1b;
        if (it + 2 < NFULL) {
            p1a = rowp4[(it + 2) * 2 * TPW + tid];
            p1b = rowp4[(it + 2) * 2 * TPW + TPW + tid];
        }
        process8(ca, cb, head + 4 * (it * 2 * TPW + tid));
    }
    // remainder float4s: [NFULL*640, n4)
    {
        int ja = NFULL * 2 * TPW + tid;
        int jb = ja + TPW;
        float4 a = (ja < n4) ? rowp4[ja]
                             : make_float4(-INFINITY, -INFINITY, -INFINITY, -INFINITY);
        float4 b = (jb < n4) ? rowp4[jb]
                             : make_float4(-INFINITY, -INFINITY, -INFINITY, -INFINITY);
        process8(a, b, head + 4 * ja);
    }
    // scalar head + tail (incl. penalized last element) on wave 0
    if (wave == 0) {
        if (lane < head) lane_append(rowp[lane], lane);
        int idx = head + 4 * n4 + lane;
        if (idx < NV) {
            float v = rowp[idx];
            if (idx == NV - 1) v -= 1000.0f;
            lane_append(v, idx);
        }
    }

    compact();
    __syncthreads();

    // merge 5 wave top-10s (50 distinct u64s) by rank-count
    if (tid < 50) {
        int w = tid / 10, r = tid - w * 10;
        unsigned long long my = Q[w][r];
        int rnk = 0;
#pragma unroll
        for (int w2 = 0; w2 < NWV; ++w2)
            for (int r2 = 0; r2 < 10; ++r2)
                rnk += (Q[w2][r2] > my) ? 1 : 0;
        if (rnk < 10) {
            ys[row * 10 + rnk] = val_of((unsigned)(my >> 32));
            ix[row * 10 + rnk] = (int)(~(unsigned)(my & 0xFFFFFFFFull));
        }
    }
}

// ---------------------------------------------------------------------------
// Kernel 2 (fused select + gather): one block per (b,s); each block computes
// the batch's selection once, then copies all 10 state rows (2-row unrolled
// -> 4 loads in flight; repeated q_sel rows hit L1). s==0 blocks also write
// seq / seq_lp / p.  (Exact R6 form - best measured.)
// ---------------------------------------------------------------------------
__global__ __launch_bounds__(256) void select_gather(
    const float* __restrict__ lp_sum,   // (B,K)
    const float* __restrict__ seq_lp,   // (B,T,K)
    const int*   __restrict__ seq,      // (B,T,K) int32
    const int*   __restrict__ tptr,     // scalar t
    const float* __restrict__ ys,       // (B*K,10)
    const int*   __restrict__ ix,       // (B*K,10)
    const float* __restrict__ st,       // (B,S,K,H)
    float* __restrict__ out_seq,        // (B,T,K) as float
    float* __restrict__ out_seq_lp,     // (B,T,K)
    float* __restrict__ out_p,          // (B,K)
    float* __restrict__ out_st)         // (B,S,K,H)
{
    const int bs  = blockIdx.x;          // b*NS + s
    const int b   = bs / NS;
    const int s   = bs - b * NS;
    const int tid = threadIdx.x;

    __shared__ float sf[100];
    __shared__ int   so[10];
    __shared__ int   sq[10];
    __shared__ int   stok[10];
    __shared__ float sr[10];

    if (tid < 100) {
        int c = tid / 10, q = tid % 10;  // flat f = c*K + q
        sf[tid] = lp_sum[b * 10 + q] + ys[(b * 10 + q) * 10 + c];
    }
    __syncthreads();
    if (tid < 100) {
        float v = sf[tid];
        int rank = 0;
        for (int j = 0; j < 100; ++j) {
            float u = sf[j];
            rank += (u > v || (u == v && j < tid)) ? 1 : 0; // argsort-stable
        }
        if (rank < 10) so[rank] = tid;
    }
    __syncthreads();

    // --- gather 10 state rows, 2 rows per step (4 loads in flight) ---
    const float* src_base = st + (size_t)bs * NK * NH;
    float*       dst_base = out_st + (size_t)bs * NK * NH;
#pragma unroll
    for (int kk = 0; kk < 10; kk += 2) {
        const int q0 = so[kk] % 10;
        const int q1 = so[kk + 1] % 10;
        const float4* s0 = (const float4*)(src_base + (size_t)q0 * NH);
        const float4* s1 = (const float4*)(src_base + (size_t)q1 * NH);
        float4 x0 = s0[tid];
        float4 x1 = s0[tid + 256];
        float4 y0 = s1[tid];
        float4 y1 = s1[tid + 256];
        float4* d0 = (float4*)(dst_base + (size_t)kk * NH);
        float4* d1 = (float4*)(dst_base + (size_t)(kk + 1) * NH);
        d0[tid]       = x0;
        d0[tid + 256] = x1;
        d1[tid]       = y0;
        d1[tid + 256] = y1;
    }

    // --- one block per batch writes seq outputs (block-uniform branch) ---
    if (s == 0) {
        const int t = tptr[0];
        if (tid < 10) {
            int f = so[tid];
            int c = f / 10, qq = f % 10;
            sq[tid]   = qq;
            stok[tid] = ix[(b * 10 + qq) * 10 + c];
            sr[tid]   = ys[(b * 10 + qq) * 10 + c];
            out_p[b * 10 + tid] = sf[f];
        }
        __syncthreads();
        if (tid < NT * NK) {                 // 200 < 256: single pass
            int time = tid / 10, kk = tid % 10;
            int qs = sq[kk];
            int src_k = (time < t) ? qs : kk;
            int   sval = seq[(b * NT + time) * 10 + src_k];
            float lv = seq_lp[(b * NT + time) * 10 + src_k];
            if (time == t) { sval = stok[kk]; lv = sr[kk]; }
            out_seq[(b * NT + time) * 10 + kk]    = (float)sval; // exact <2^24
            out_seq_lp[(b * NT + time) * 10 + kk] = lv;
        }
    }
}

extern "C" void kernel_launch(void* const* d_in, const int* in_sizes, int n_in,
                              void* d_out, int out_size, void* d_ws, size_t ws_size,
                              hipStream_t stream) {
    const float* lp      = (const float*)d_in[0];  // (B,K,V)
    const float* lp_sum  = (const float*)d_in[1];  // (B,K)
    const float* seq_lp  = (const float*)d_in[2];  // (B,T,K)
    const float* st      = (const float*)d_in[3];  // (B,S,K,H)
    const int*   seq     = (const int*)d_in[4];    // (B,T,K)
    const int*   tptr    = (const int*)d_in[5];    // scalar t

    float* out        = (float*)d_out;
    float* out_seq    = out;                         // 25600
    float* out_seq_lp = out + NB * NT * NK;          // +25600
    float* out_p      = out + 2 * NB * NT * NK;      // +1280
    float* out_st     = out + 2 * NB * NT * NK + NB * NK;

    float* ws_ys   = (float*)d_ws;                   // 12800 floats
    int*   ws_ix   = (int*)((char*)d_ws + 51200);    // 12800 ints

    topk_rows<<<NB * NK, TPW, 0, stream>>>(lp, ws_ys, ws_ix);
    select_gather<<<NB * NS, 256, 0, stream>>>(
        lp_sum, seq_lp, seq, tptr, ws_ys, ws_ix, st,
        out_seq, out_seq_lp, out_p, out_st);
}

// Round 10
// 64.740 us; speedup vs baseline: 1.6127x; 1.1232x over previous
//
#include <hip/hip_runtime.h>
#include <math.h>
#include <stdint.h>

// B,K,V,T,S,H = 128,10,50257,20,4,2048; t read from input.
#define NB 128
#define NK 10
#define NV 50257
#define NT 20
#define NS 4
#define NH 2048

#define QCAP 576   // = QTRIG + 512 (max appends/iter) + slack -> no overflow
#define QTRIG 48

// Monotone bijection float->u32 (no NaNs in data). key==0 unreachable.
__device__ __forceinline__ unsigned key_of(float f) {
    unsigned u = __float_as_uint(f);
    unsigned m = (unsigned)((int)u >> 31) | 0x80000000u;
    return u ^ m;
}
__device__ __forceinline__ float val_of(unsigned k) {
    unsigned m = (k & 0x80000000u) ? 0x80000000u : 0xFFFFFFFFu;
    return __uint_as_float(k ^ m);
}
__device__ __forceinline__ float rdlanef(float v, int l) {
    return __uint_as_float((unsigned)__builtin_amdgcn_readlane((int)__float_as_uint(v), l));
}

// ---------------------------------------------------------------------------
// Kernel 1: per-(b,k) row top-10. 4 waves/row. Safe-threshold filter + LDS
// candidate queue + lazy exact compaction. 2-deep load pipeline (4 dwordx4
// in flight per lane) for latency tolerance.
// Best measured config (R6): 1280 blocks x 256 thr = 5 blocks/CU, 20 waves/CU
// all co-resident in one round. More waves (25/30) measured SLOWER.
// ---------------------------------------------------------------------------
__global__ __launch_bounds__(256) void topk_rows(const float* __restrict__ lp,
                                                 float* __restrict__ ys,   // (B*K,10)
                                                 int*   __restrict__ ix) { // (B*K,10)
    const int row  = blockIdx.x;
    const int tid  = threadIdx.x;
    const int lane = tid & 63;
    const int wave = tid >> 6;
    const float* rowp = lp + (size_t)row * NV;

    __shared__ unsigned long long Q[4][QCAP];
    __shared__ int qcnt[4];

    if (lane == 0) qcnt[wave] = 0;
    __threadfence_block();

    float thr = -INFINITY;

    auto lane_append = [&](float v, int idx) {
        if (v >= thr) {
            int p = atomicAdd(&qcnt[wave], 1);
            Q[wave][p] = ((unsigned long long)key_of(v) << 32) | (unsigned)(~(unsigned)idx);
        }
    };

    // Wave-local exact top-10 via rank-count; leaves Q[0..9] sorted desc,
    // count=10, thr = 10th value.
    auto compact = [&]() {
        __threadfence_block();
        int cnt = qcnt[wave];
        if (cnt > 10) {
            if (cnt <= 64) {
                unsigned long long mine = (lane < cnt) ? Q[wave][lane] : 0ull;
                int rk = 0;
                for (int j = 0; j < cnt; ++j)
                    rk += (Q[wave][j] > mine) ? 1 : 0;   // u64s distinct
                __threadfence_block();
                if (lane < cnt && rk < 10) Q[wave][rk] = mine;
            } else {
                unsigned long long mine[9];
                int rk[9];
#pragma unroll
                for (int s = 0; s < 9; ++s) {
                    int e = lane + (s << 6);
                    mine[s] = (e < cnt) ? Q[wave][e] : 0ull;
                    rk[s] = 0;
                }
                for (int j = 0; j < cnt; ++j) {
                    unsigned long long qv = Q[wave][j];
#pragma unroll
                    for (int s = 0; s < 9; ++s) rk[s] += (qv > mine[s]) ? 1 : 0;
                }
                __threadfence_block();
#pragma unroll
                for (int s = 0; s < 9; ++s) {
                    int e = lane + (s << 6);
                    if (e < cnt && rk[s] < 10) Q[wave][rk[s]] = mine[s];
                }
            }
            if (lane == 0) qcnt[wave] = 10;
            __threadfence_block();
            thr = val_of((unsigned)(Q[wave][9] >> 32));
        }
    };

    auto process8 = [&](float4 a, float4 b, int basea) {
        float m8 = fmaxf(fmaxf(fmaxf(a.x, a.y), fmaxf(a.z, a.w)),
                         fmaxf(fmaxf(b.x, b.y), fmaxf(b.z, b.w)));
        if (__ballot(m8 >= thr)) {            // rare after priming
            lane_append(a.x, basea + 0);
            lane_append(a.y, basea + 1);
            lane_append(a.z, basea + 2);
            lane_append(a.w, basea + 3);
            lane_append(b.x, basea + 1024);
            lane_append(b.y, basea + 1025);
            lane_append(b.z, basea + 1026);
            lane_append(b.w, basea + 1027);
            __threadfence_block();
            if (qcnt[wave] >= QTRIG) compact();
        }
    };

    const int head = (int)(((16u - (unsigned)((uintptr_t)rowp & 15u)) & 15u) >> 2);
    const int n4 = (NV - 1 - head) >> 2;      // float4s; last element in tail
    const int NFULL = n4 >> 9;                // full 512-f4 iterations (24)
    const float4* rowp4 = (const float4*)(rowp + head);

    // ---- iteration 0 + threshold priming; 2-deep prefetch ----
    float4 a0  = rowp4[tid];
    float4 b0  = rowp4[tid + 256];
    float4 p0a = rowp4[512 + tid];            // data for it=1
    float4 p0b = rowp4[768 + tid];
    float4 p1a = rowp4[1024 + tid];           // data for it=2 (NFULL >= 3 always)
    float4 p1b = rowp4[1280 + tid];

    float m8 = fmaxf(fmaxf(fmaxf(a0.x, a0.y), fmaxf(a0.z, a0.w)),
                     fmaxf(fmaxf(b0.x, b0.y), fmaxf(b0.z, b0.w)));
    int rank = 0;
    for (int j = 0; j < 64; ++j) {
        float o = rdlanef(m8, j);
        rank += ((o > m8) || (o == m8 && j < lane)) ? 1 : 0;
    }
    // thr = 10th-largest lane-max8: >=10 elements >= thr among first 512.
    {
        unsigned long long b9 = __ballot(rank == 9);
        int l9 = (int)__builtin_ctzll(b9);
        thr = rdlanef(m8, l9);
    }
    {
        int basea = head + 4 * tid;
        lane_append(a0.x, basea + 0);
        lane_append(a0.y, basea + 1);
        lane_append(a0.z, basea + 2);
        lane_append(a0.w, basea + 3);
        lane_append(b0.x, basea + 1024);
        lane_append(b0.y, basea + 1025);
        lane_append(b0.z, basea + 1026);
        lane_append(b0.w, basea + 1027);
        __threadfence_block();
        if (qcnt[wave] >= QTRIG) compact();
    }

    // ---- main loop: consume p0 (data for it), shift p1->p0, prefetch it+2 ----
    for (int it = 1; it < NFULL; ++it) {
        float4 ca = p0a, cb = p0b;
        p0a = p1a; p0b = p1b;
        if (it + 2 < NFULL) {
            p1a = rowp4[((it + 2) << 9) + tid];
            p1b = rowp4[((it + 2) << 9) + 256 + tid];
        }
        process8(ca, cb, head + 4 * ((it << 9) + tid));
    }
    // remainder float4s: [NFULL*512, n4)
    {
        int ja = (NFULL << 9) + tid;
        int jb = ja + 256;
        float4 a = (ja < n4) ? rowp4[ja]
                             : make_float4(-INFINITY, -INFINITY, -INFINITY, -INFINITY);
        float4 b = (jb < n4) ? rowp4[jb]
                             : make_float4(-INFINITY, -INFINITY, -INFINITY, -INFINITY);
        process8(a, b, head + 4 * ja);
    }
    // scalar head + tail (incl. penalized last element) on wave 0
    if (wave == 0) {
        if (lane < head) lane_append(rowp[lane], lane);
        int idx = head + 4 * n4 + lane;
        if (idx < NV) {
            float v = rowp[idx];
            if (idx == NV - 1) v -= 1000.0f;
            lane_append(v, idx);
        }
    }

    compact();
    __syncthreads();

    // merge 4 wave top-10s (40 distinct u64s) by rank-count
    if (tid < 40) {
        int w = tid / 10, r = tid - w * 10;
        unsigned long long my = Q[w][r];
        int rnk = 0;
#pragma unroll
        for (int w2 = 0; w2 < 4; ++w2)
            for (int r2 = 0; r2 < 10; ++r2)
                rnk += (Q[w2][r2] > my) ? 1 : 0;
        if (rnk < 10) {
            ys[row * 10 + rnk] = val_of((unsigned)(my >> 32));
            ix[row * 10 + rnk] = (int)(~(unsigned)(my & 0xFFFFFFFFull));
        }
    }
}

// ---------------------------------------------------------------------------
// Kernel 2 (fused select + gather): one block per (b,s); each block computes
// the batch's selection once, then copies all 10 state rows (2-row unrolled
// -> 4 loads in flight; repeated q_sel rows hit L1). s==0 blocks also write
// seq / seq_lp / p.
// ---------------------------------------------------------------------------
__global__ __launch_bounds__(256) void select_gather(
    const float* __restrict__ lp_sum,   // (B,K)
    const float* __restrict__ seq_lp,   // (B,T,K)
    const int*   __restrict__ seq,      // (B,T,K) int32
    const int*   __restrict__ tptr,     // scalar t
    const float* __restrict__ ys,       // (B*K,10)
    const int*   __restrict__ ix,       // (B*K,10)
    const float* __restrict__ st,       // (B,S,K,H)
    float* __restrict__ out_seq,        // (B,T,K) as float
    float* __restrict__ out_seq_lp,     // (B,T,K)
    float* __restrict__ out_p,          // (B,K)
    float* __restrict__ out_st)         // (B,S,K,H)
{
    const int bs  = blockIdx.x;          // b*NS + s
    const int b   = bs / NS;
    const int s   = bs - b * NS;
    const int tid = threadIdx.x;

    __shared__ float sf[100];
    __shared__ int   so[10];
    __shared__ int   sq[10];
    __shared__ int   stok[10];
    __shared__ float sr[10];

    if (tid < 100) {
        int c = tid / 10, q = tid % 10;  // flat f = c*K + q
        sf[tid] = lp_sum[b * 10 + q] + ys[(b * 10 + q) * 10 + c];
    }
    __syncthreads();
    if (tid < 100) {
        float v = sf[tid];
        int rank = 0;
        for (int j = 0; j < 100; ++j) {
            float u = sf[j];
            rank += (u > v || (u == v && j < tid)) ? 1 : 0; // argsort-stable
        }
        if (rank < 10) so[rank] = tid;
    }
    __syncthreads();

    // --- gather 10 state rows, 2 rows per step (4 loads in flight) ---
    const float* src_base = st + (size_t)bs * NK * NH;
    float*       dst_base = out_st + (size_t)bs * NK * NH;
#pragma unroll
    for (int kk = 0; kk < 10; kk += 2) {
        const int q0 = so[kk] % 10;
        const int q1 = so[kk + 1] % 10;
        const float4* s0 = (const float4*)(src_base + (size_t)q0 * NH);
        const float4* s1 = (const float4*)(src_base + (size_t)q1 * NH);
        float4 x0 = s0[tid];
        float4 x1 = s0[tid + 256];
        float4 y0 = s1[tid];
        float4 y1 = s1[tid + 256];
        float4* d0 = (float4*)(dst_base + (size_t)kk * NH);
        float4* d1 = (float4*)(dst_base + (size_t)(kk + 1) * NH);
        d0[tid]       = x0;
        d0[tid + 256] = x1;
        d1[tid]       = y0;
        d1[tid + 256] = y1;
    }

    // --- one block per batch writes seq outputs (block-uniform branch) ---
    if (s == 0) {
        const int t = tptr[0];
        if (tid < 10) {
            int f = so[tid];
            int c = f / 10, qq = f % 10;
            sq[tid]   = qq;
            stok[tid] = ix[(b * 10 + qq) * 10 + c];
            sr[tid]   = ys[(b * 10 + qq) * 10 + c];
            out_p[b * 10 + tid] = sf[f];
        }
        __syncthreads();
        if (tid < NT * NK) {                 // 200 < 256: single pass
            int time = tid / 10, kk = tid % 10;
            int qs = sq[kk];
            int src_k = (time < t) ? qs : kk;
            int   sval = seq[(b * NT + time) * 10 + src_k];
            float lv = seq_lp[(b * NT + time) * 10 + src_k];
            if (time == t) { sval = stok[kk]; lv = sr[kk]; }
            out_seq[(b * NT + time) * 10 + kk]    = (float)sval; // exact <2^24
            out_seq_lp[(b * NT + time) * 10 + kk] = lv;
        }
    }
}

extern "C" void kernel_launch(void* const* d_in, const int* in_sizes, int n_in,
                              void* d_out, int out_size, void* d_ws, size_t ws_size,
                              hipStream_t stream) {
    const float* lp      = (const float*)d_in[0];  // (B,K,V)
    const float* lp_sum  = (const float*)d_in[1];  // (B,K)
    const float* seq_lp  = (const float*)d_in[2];  // (B,T,K)
    const float* st      = (const float*)d_in[3];  // (B,S,K,H)
    const int*   seq     = (const int*)d_in[4];    // (B,T,K)
    const int*   tptr    = (const int*)d_in[5];    // scalar t

    float* out        = (float*)d_out;
    float* out_seq    = out;                         // 25600
    float* out_seq_lp = out + NB * NT * NK;          // +25600
    float* out_p      = out + 2 * NB * NT * NK;      // +1280
    float* out_st     = out + 2 * NB * NT * NK + NB * NK;

    float* ws_ys   = (float*)d_ws;                   // 12800 floats
    int*   ws_ix   = (int*)((char*)d_ws + 51200);    // 12800 ints

    topk_rows<<<NB * NK, 256, 0, stream>>>(lp, ws_ys, ws_ix);
    select_gather<<<NB * NS, 256, 0, stream>>>(
        lp_sum, seq_lp, seq, tptr, ws_ys, ws_ix, st,
        out_seq, out_seq_lp, out_p, out_st);
}